// Round 14
// baseline (119.249 us; speedup 1.0000x reference)
//
#include <hip/hip_runtime.h>
#include <hip/hip_bf16.h>
#include <hip/hip_fp16.h>
#include <math.h>

#define S 2048
#define DM 1024
#define QIN 512
#define HI 16
#define DI 64
#define NH 8
#define TOPK 128
#define LN_EPS 1e-5f
#define KP 8            // k_part split-K factor
#define KVSZ (S * NH * 64)   // elements per K/V replica (1,048,576)

typedef float f32x4 __attribute__((ext_vector_type(4)));
typedef short s16x8 __attribute__((ext_vector_type(8)));

__device__ __forceinline__ float wave_sum(float v){
#pragma unroll
  for (int o = 32; o; o >>= 1) v += __shfl_xor(v, o);
  return v;
}
__device__ __forceinline__ float wave_max(float v){
#pragma unroll
  for (int o = 32; o; o >>= 1) v = fmaxf(v, __shfl_xor(v, o));
  return v;
}
__device__ __forceinline__ unsigned short f2bf(float x){
  unsigned u = __float_as_uint(x);
  unsigned r = u + 0x7FFFu + ((u >> 16) & 1u);   // RN-even
  return (unsigned short)(r >> 16);
}
__device__ __forceinline__ float bf2f(unsigned short s){
  return __uint_as_float(((unsigned)s) << 16);
}
__device__ __forceinline__ unsigned short f2h(float x){
  return __half_as_ushort(__float2half_rn(x));
}
union UH2 { unsigned int u; __half2 h; };
__device__ __forceinline__ __half2 as_half2(unsigned int u){ UH2 x; x.u = u; return x.h; }

// 3-term (2-split): (ah+al)(bh+bl) dropping al*bl  [r4-r8 proven for qi]
#define MFMA3(ACC, AH, AL, BH, BL) \
  ACC = __builtin_amdgcn_mfma_f32_16x16x32_bf16(AH, BH, ACC, 0, 0, 0); \
  ACC = __builtin_amdgcn_mfma_f32_16x16x32_bf16(AH, BL, ACC, 0, 0, 0); \
  ACC = __builtin_amdgcn_mfma_f32_16x16x32_bf16(AL, BH, ACC, 0, 0, 0);

// 6-term (3-split): rel err ~2^-26, f32-class  [r11/r13 proven for scores]
#define MFMA6(ACC, AH, AM, AL, BH, BM, BL) \
  ACC = __builtin_amdgcn_mfma_f32_16x16x32_bf16(AH, BH, ACC, 0, 0, 0); \
  ACC = __builtin_amdgcn_mfma_f32_16x16x32_bf16(AH, BM, ACC, 0, 0, 0); \
  ACC = __builtin_amdgcn_mfma_f32_16x16x32_bf16(AM, BH, ACC, 0, 0, 0); \
  ACC = __builtin_amdgcn_mfma_f32_16x16x32_bf16(AH, BL, ACC, 0, 0, 0); \
  ACC = __builtin_amdgcn_mfma_f32_16x16x32_bf16(AL, BH, ACC, 0, 0, 0); \
  ACC = __builtin_amdgcn_mfma_f32_16x16x32_bf16(AM, BM, ACC, 0, 0, 0);

// ======== F1: fused [part-f32 (256) | prep-convert (3072, K/V -> 8 XCD replicas) | wq-trsplit (512)] ========
__global__ __launch_bounds__(256) void k_f1(const float* __restrict__ x,
                                            const float* __restrict__ wk,
                                            const float* __restrict__ ww,
                                            float* __restrict__ part,
                                            const float* __restrict__ qin,
                                            unsigned short* __restrict__ Ah,
                                            unsigned short* __restrict__ Al,
                                            const float* __restrict__ k,
                                            unsigned short* __restrict__ kh,
                                            const float* __restrict__ v,
                                            unsigned short* __restrict__ vh,
                                            const float* __restrict__ wq,
                                            unsigned short* __restrict__ Bh,
                                            unsigned short* __restrict__ Bl){
  __shared__ float As[32][68];
  __shared__ float Bs[32][84];
  const int bid = blockIdx.x;
  const int t = threadIdx.x;

  if (bid < 256){
    // ---- part: split-K f32 GEMM x(2048x1024) @ [wk|ww](1024x80)  [exact] ----
    const int kp = bid & 7;
    const int bm = bid >> 3;
    const int m0 = bm * 64;
    const int tm = (t & 15) * 4;
    const int tn = (t >> 4) * 5;
    float acc[4][5];
#pragma unroll
    for (int i = 0; i < 4; i++)
#pragma unroll
      for (int j = 0; j < 5; j++) acc[i][j] = 0.f;

    for (int kb = 0; kb < (DM / KP) / 32; ++kb){
      const int k0 = kp * (DM / KP) + kb * 32;
#pragma unroll
      for (int i = 0; i < 2; i++){
        int u = t + i * 256;
        int m = u >> 3, c4 = u & 7;
        float4 a = *(const float4*)&x[(size_t)(m0 + m) * DM + k0 + c4 * 4];
        As[c4*4+0][m] = a.x; As[c4*4+1][m] = a.y; As[c4*4+2][m] = a.z; As[c4*4+3][m] = a.w;
      }
#pragma unroll
      for (int i = 0; i < 10; i++){
        int u = t + i * 256;
        int kk = u / 80, nn = u % 80;
        float val = (nn < 64) ? wk[(size_t)(k0 + kk) * 64 + nn]
                              : ww[(size_t)(k0 + kk) * 16 + (nn - 64)];
        Bs[kk][nn] = val;
      }
      __syncthreads();
#pragma unroll
      for (int kk = 0; kk < 32; ++kk){
        float4 a = *(const float4*)&As[kk][tm];
        float av[4] = {a.x, a.y, a.z, a.w};
        float bb[5];
#pragma unroll
        for (int j = 0; j < 5; j++) bb[j] = Bs[kk][tn + j];
#pragma unroll
        for (int i = 0; i < 4; i++)
#pragma unroll
          for (int j = 0; j < 5; j++) acc[i][j] = fmaf(av[i], bb[j], acc[i][j]);
      }
      __syncthreads();
    }
    float* dst = part + (size_t)kp * S * 80;
#pragma unroll
    for (int i = 0; i < 4; i++)
#pragma unroll
      for (int j = 0; j < 5; j++)
        dst[(size_t)(m0 + tm + i) * 80 + tn + j] = acc[i][j];
    return;
  }

  if (bid < 256 + 3072){
    // ---- prep-convert: 2-split bf16(q_input); f16(K), f16(V) written to 8 XCD replicas ----
    const int SEG0 = S * QIN / 4;      // 262144
    const int SEG1 = KVSZ / 4;         // 262144
    int id = (bid - 256) * 256 + t;
    if (id < SEG0){
      float4 f = ((const float4*)qin)[id];
      ushort4 h, lo;
      h.x = f2bf(f.x); lo.x = f2bf(f.x - bf2f(h.x));
      h.y = f2bf(f.y); lo.y = f2bf(f.y - bf2f(h.y));
      h.z = f2bf(f.z); lo.z = f2bf(f.z - bf2f(h.z));
      h.w = f2bf(f.w); lo.w = f2bf(f.w - bf2f(h.w));
      ((ushort4*)Ah)[id] = h;
      ((ushort4*)Al)[id] = lo;
    } else if (id < SEG0 + SEG1){
      int j = id - SEG0;
      float4 f = ((const float4*)k)[j];
      ushort4 o;
      o.x = f2h(f.x); o.y = f2h(f.y); o.z = f2h(f.z); o.w = f2h(f.w);
#pragma unroll
      for (int c = 0; c < 8; ++c)
        ((ushort4*)(kh + (size_t)c * KVSZ))[j] = o;
    } else {
      int j = id - SEG0 - SEG1;
      float4 f = ((const float4*)v)[j];
      ushort4 o;
      o.x = f2h(f.x); o.y = f2h(f.y); o.z = f2h(f.z); o.w = f2h(f.w);
#pragma unroll
      for (int c = 0; c < 8; ++c)
        ((ushort4*)(vh + (size_t)c * KVSZ))[j] = o;
    }
    return;
  }

  // ---- wq (512x1024) -> transposed 2-split bf16 [n][k] ----
  {
    unsigned short (*lh)[33] = (unsigned short(*)[33])&As[0][0];
    unsigned short (*ll)[33] = (unsigned short(*)[33])&Bs[0][0];
    const int b2 = bid - 3328;          // 0..511
    const int k0 = (b2 & 15) * 32;
    const int n0 = (b2 >> 4) * 32;
    const int c = t & 31, r8 = t >> 5;
#pragma unroll
    for (int i = 0; i < 4; ++i){
      int kk = r8 + i * 8;
      float wv = wq[(size_t)(k0 + kk) * 1024 + n0 + c];
      unsigned short h = f2bf(wv);
      lh[c][kk] = h;
      ll[c][kk] = f2bf(wv - bf2f(h));
    }
    __syncthreads();
    const int kk = t & 31, nl = t >> 5;
#pragma unroll
    for (int i = 0; i < 4; ++i){
      int nn = nl + i * 8;
      Bh[(size_t)(n0 + nn) * QIN + k0 + kk] = lh[nn][kk];
      Bl[(size_t)(n0 + nn) * QIN + k0 + kk] = ll[nn][kk];
    }
  }
}

// ======== F2: fused [lnw -> ki-3split + wgt (512 blocks) | qi 3-term split-K=2 (1024 blocks)] ========
__global__ __launch_bounds__(256) void k_f2(const float* __restrict__ part,
                                            const float* __restrict__ g,
                                            const float* __restrict__ b,
                                            unsigned short* __restrict__ kih,
                                            unsigned short* __restrict__ kim,
                                            unsigned short* __restrict__ kil,
                                            float* __restrict__ wgt,
                                            const unsigned short* __restrict__ Ah,
                                            const unsigned short* __restrict__ Al,
                                            const unsigned short* __restrict__ Bh,
                                            const unsigned short* __restrict__ Bl,
                                            float* __restrict__ qi){
  const int bid = blockIdx.x;
  if (bid < 512){
    // ---- lnw: reduce KP partials, LayerNorm -> ki 3-split; wgt from cols 64..79 (exact f32) ----
    const int s = bid * 4 + (threadIdx.x >> 6);
    const int l = threadIdx.x & 63;
    float kv = 0.f;
#pragma unroll
    for (int p = 0; p < KP; p++) kv += part[(size_t)p * S * 80 + (size_t)s * 80 + l];
    float wv = 0.f;
    if (l < 16){
#pragma unroll
      for (int p = 0; p < KP; p++) wv += part[(size_t)p * S * 80 + (size_t)s * 80 + 64 + l];
    }
    float mu = wave_sum(kv) * (1.f / 64.f);
    float d  = kv - mu;
    float var = wave_sum(d * d) * (1.f / 64.f);
    float o = d * (1.f / sqrtf(var + LN_EPS)) * g[l] + b[l];
    unsigned short h = f2bf(o);
    float r1 = o - bf2f(h);
    unsigned short m = f2bf(r1);
    kih[(size_t)s * 64 + l] = h;
    kim[(size_t)s * 64 + l] = m;
    kil[(size_t)s * 64 + l] = f2bf(r1 - bf2f(m));
    if (l < 16) wgt[(size_t)s * 16 + l] = wv * 0.25f;   // HI^-0.5
    return;
  }
  // ---- qi = q_input @ w_q, 3-term MFMA, split-K=2 -> qi[kp] partials ----
  const int b2 = bid - 512;               // 0..1023
  const int kp = b2 & 1;
  const int bidx = b2 >> 1;               // 0..511
  const int bn = bidx & 15;
  const int bm = bidx >> 4;
  const int w = threadIdx.x >> 6, l = threadIdx.x & 63;
  const int r = l & 15, kg = l >> 4;
  const int m0 = bm * 64 + (w >> 1) * 32;
  const int n0 = bn * 64 + (w & 1) * 32;
  const int kbase = kp * 256;
  f32x4 acc00 = {0,0,0,0}, acc01 = {0,0,0,0}, acc10 = {0,0,0,0}, acc11 = {0,0,0,0};
  const size_t aoff = (size_t)(m0 + r) * QIN + kbase + kg * 8;
  const size_t boff = (size_t)(n0 + r) * QIN + kbase + kg * 8;
#pragma unroll 4
  for (int k0 = 0; k0 < 256; k0 += 32){
    s16x8 ah0 = *(const s16x8*)(Ah + aoff + k0);
    s16x8 ah1 = *(const s16x8*)(Ah + aoff + 16 * QIN + k0);
    s16x8 al0 = *(const s16x8*)(Al + aoff + k0);
    s16x8 al1 = *(const s16x8*)(Al + aoff + 16 * QIN + k0);
    s16x8 bh0 = *(const s16x8*)(Bh + boff + k0);
    s16x8 bh1 = *(const s16x8*)(Bh + boff + 16 * QIN + k0);
    s16x8 bl0 = *(const s16x8*)(Bl + boff + k0);
    s16x8 bl1 = *(const s16x8*)(Bl + boff + 16 * QIN + k0);
    MFMA3(acc00, ah0, al0, bh0, bl0)
    MFMA3(acc01, ah0, al0, bh1, bl1)
    MFMA3(acc10, ah1, al1, bh0, bl0)
    MFMA3(acc11, ah1, al1, bh1, bl1)
  }
  float* qip = qi + (size_t)kp * S * 1024;
#pragma unroll
  for (int j = 0; j < 4; ++j){
    qip[(size_t)(m0 +  0 + kg * 4 + j) * 1024 + n0 +  0 + r] = acc00[j];
    qip[(size_t)(m0 +  0 + kg * 4 + j) * 1024 + n0 + 16 + r] = acc01[j];
    qip[(size_t)(m0 + 16 + kg * 4 + j) * 1024 + n0 +  0 + r] = acc10[j];
    qip[(size_t)(m0 + 16 + kg * 4 + j) * 1024 + n0 + 16 + r] = acc11[j];
  }
}

// ======== F3: qeff (512 blocks) — sum qi partials, weighted head-sum, emit qe 3-split ========
__global__ __launch_bounds__(256) void k_f3(const float* __restrict__ qi,
                                            const float* __restrict__ wgt,
                                            unsigned short* __restrict__ qeh,
                                            unsigned short* __restrict__ qem,
                                            unsigned short* __restrict__ qel){
  const int id = blockIdx.x * 256 + threadIdx.x;  // S*64
  const int s = id >> 6, d = id & 63;
  const float* qiA = qi;
  const float* qiB = qi + (size_t)S * 1024;
  float acc = 0.f;
#pragma unroll
  for (int h = 0; h < 16; h++){
    float qv = qiA[(size_t)s * 1024 + h * 64 + d] + qiB[(size_t)s * 1024 + h * 64 + d];
    acc = fmaf(wgt[(size_t)s * 16 + h], qv, acc);
  }
  acc *= 0.125f;   // DI^-0.5
  unsigned short hh = f2bf(acc);
  float r1 = acc - bf2f(hh);
  unsigned short mm = f2bf(r1);
  qeh[(size_t)s * 64 + d] = hh;
  qem[(size_t)s * 64 + d] = mm;
  qel[(size_t)s * 64 + d] = f2bf(r1 - bf2f(mm));
}

// ---------------- kernel 5: scores = q_eff @ ki^T via 6-term 3-split MFMA (triangular) ----------------
__global__ __launch_bounds__(256) void k_scores(const unsigned short* __restrict__ qeh,
                                                const unsigned short* __restrict__ qem,
                                                const unsigned short* __restrict__ qel,
                                                const unsigned short* __restrict__ kih,
                                                const unsigned short* __restrict__ kim,
                                                const unsigned short* __restrict__ kil,
                                                float* __restrict__ sc){
  const int bj = blockIdx.x, bi = blockIdx.y;
  if (bj > bi) return;
  const int w = threadIdx.x >> 6, l = threadIdx.x & 63;
  const int r = l & 15, kg = l >> 4;
  const int m0 = bi * 64 + (w >> 1) * 32;
  const int n0 = bj * 64 + (w & 1) * 32;
  f32x4 acc00 = {0,0,0,0}, acc01 = {0,0,0,0}, acc10 = {0,0,0,0}, acc11 = {0,0,0,0};
  const size_t aoff = (size_t)(m0 + r) * 64 + kg * 8;
  const size_t boff = (size_t)(n0 + r) * 64 + kg * 8;
#pragma unroll
  for (int k0 = 0; k0 < 64; k0 += 32){
    s16x8 ah0 = *(const s16x8*)(qeh + aoff + k0);
    s16x8 ah1 = *(const s16x8*)(qeh + aoff + 16 * 64 + k0);
    s16x8 am0 = *(const s16x8*)(qem + aoff + k0);
    s16x8 am1 = *(const s16x8*)(qem + aoff + 16 * 64 + k0);
    s16x8 al0 = *(const s16x8*)(qel + aoff + k0);
    s16x8 al1 = *(const s16x8*)(qel + aoff + 16 * 64 + k0);
    s16x8 bh0 = *(const s16x8*)(kih + boff + k0);
    s16x8 bh1 = *(const s16x8*)(kih + boff + 16 * 64 + k0);
    s16x8 bm0 = *(const s16x8*)(kim + boff + k0);
    s16x8 bm1 = *(const s16x8*)(kim + boff + 16 * 64 + k0);
    s16x8 bl0 = *(const s16x8*)(kil + boff + k0);
    s16x8 bl1 = *(const s16x8*)(kil + boff + 16 * 64 + k0);
    MFMA6(acc00, ah0, am0, al0, bh0, bm0, bl0)
    MFMA6(acc01, ah0, am0, al0, bh1, bm1, bl1)
    MFMA6(acc10, ah1, am1, al1, bh0, bm0, bl0)
    MFMA6(acc11, ah1, am1, al1, bh1, bm1, bl1)
  }
#pragma unroll
  for (int j = 0; j < 4; ++j){
    sc[(size_t)(m0 +  0 + kg * 4 + j) * S + n0 +  0 + r] = acc00[j];
    sc[(size_t)(m0 +  0 + kg * 4 + j) * S + n0 + 16 + r] = acc01[j];
    sc[(size_t)(m0 + 16 + kg * 4 + j) * S + n0 +  0 + r] = acc10[j];
    sc[(size_t)(m0 + 16 + kg * 4 + j) * S + n0 + 16 + r] = acc11[j];
  }
}

// ---------------- kernel 6: per-row causal top-128 — radix select with candidate compaction ----------------
__global__ __launch_bounds__(256) void k_topk(const float* __restrict__ sc,
                                              int* __restrict__ idx,
                                              int* __restrict__ cnt){
  const int i = blockIdx.x, t = threadIdx.x;
  const int w = t >> 6, l = t & 63;
  const int n = i + 1;           // valid causal candidates
  int* outr = idx + (size_t)i * TOPK;
  if (n <= TOPK){
    for (int m = t; m < n; m += 256) outr[m] = m;
    if (t == 0) cnt[i] = n;
    return;
  }
  __shared__ unsigned int keys[S];
  __shared__ int lA[S];
  __shared__ int lB[S];
  __shared__ int hist[256];
  __shared__ int wtot[4];
  __shared__ int s_b, s_above, s_out, s_m;
  hist[t] = 0;
  if (t == 0) s_out = 0;
  __syncthreads();
  for (int j = t; j < n; j += 256){
    unsigned int u = __float_as_uint(sc[(size_t)i * S + j]);
    unsigned int kk = (u & 0x80000000u) ? ~u : (u | 0x80000000u);   // order-preserving key
    keys[j] = kk;
    atomicAdd(&hist[kk >> 24], 1);    // top-byte histogram fused into load
  }
  __syncthreads();
  int rem = TOPK;
  {
    const int h = hist[t];
    int vsc = h;
#pragma unroll
    for (int off = 1; off < 64; off <<= 1){
      int u = __shfl_down(vsc, off);
      if (l + off < 64) vsc += u;
    }
    if (l == 0) wtot[w] = vsc;
    __syncthreads();
    int later = 0;
#pragma unroll
    for (int ww = 1; ww < 4; ++ww) if (ww > w) later += wtot[ww];
    const int excl = vsc + later - h;
    if (excl < rem && excl + h >= rem){ s_b = t; s_above = excl; }
    __syncthreads();
  }
  int b = s_b;
  rem -= s_above;
  if (t == 0) s_m = 0;
  __syncthreads();
  for (int j = t; j < n; j += 256){
    int by = keys[j] >> 24;
    if (by > b){ int p = atomicAdd(&s_out, 1); outr[p] = j; }
    else if (by == b){ int p = atomicAdd(&s_m, 1); lA[p] = j; }
  }
  __syncthreads();
  int m = s_m;
  int* Lsrc = lA; int* Ldst = lB;
  bool done = false;
  if (m == rem){
    int base = TOPK - rem;
    for (int u = t; u < m; u += 256) outr[base + u] = Lsrc[u];
    done = true;
  }
  for (int p = 2; p >= 0 && !done; --p){
    const int sh = p * 8;
    __syncthreads();
    hist[t] = 0;
    __syncthreads();
    for (int u = t; u < m; u += 256) atomicAdd(&hist[(keys[Lsrc[u]] >> sh) & 255], 1);
    __syncthreads();
    {
      const int h = hist[t];
      int vsc = h;
#pragma unroll
      for (int off = 1; off < 64; off <<= 1){
        int u = __shfl_down(vsc, off);
        if (l + off < 64) vsc += u;
      }
      if (l == 0) wtot[w] = vsc;
      __syncthreads();
      int later = 0;
#pragma unroll
      for (int ww = 1; ww < 4; ++ww) if (ww > w) later += wtot[ww];
      const int excl = vsc + later - h;
      if (excl < rem && excl + h >= rem){ s_b = t; s_above = excl; }
      __syncthreads();
    }
    b = s_b;
    rem -= s_above;
    if (t == 0) s_m = 0;
    __syncthreads();
    for (int u = t; u < m; u += 256){
      int j = Lsrc[u]; int by = (keys[j] >> sh) & 255;
      if (by > b){ int p2 = atomicAdd(&s_out, 1); outr[p2] = j; }
      else if (by == b){ int p2 = atomicAdd(&s_m, 1); Ldst[p2] = j; }
    }
    __syncthreads();
    m = s_m;
    { int* tmp = Lsrc; Lsrc = Ldst; Ldst = tmp; }
    if (m == rem){
      int base = TOPK - rem;
      for (int u = t; u < m; u += 256) outr[base + u] = Lsrc[u];
      done = true;
    }
  }
  if (!done && t == 0){
    int base = TOPK - rem;
    for (int a = 0; a < rem; ++a){
      int mn = 1 << 30, pos = -1;
      for (int u = 0; u < m; ++u){ int j = Lsrc[u]; if (j < mn){ mn = j; pos = u; } }
      outr[base + a] = mn; Lsrc[pos] = 1 << 30;
    }
  }
  if (t == 0) cnt[i] = TOPK;
}

// ---------------- kernel 7: gathered sparse attention — f16 K/V (XCD-local replica), barrier-free ----------------
__global__ __launch_bounds__(256) void k_attn(const float* __restrict__ q,
                                              const unsigned short* __restrict__ kh,
                                              const unsigned short* __restrict__ vh,
                                              const int* __restrict__ idx,
                                              const int* __restrict__ cnt,
                                              float* __restrict__ out){
  const int i = blockIdx.x;
  const int w = threadIdx.x >> 6, l = threadIdx.x & 63;
  const int n = cnt[i];
  const int* irow = idx + (size_t)i * TOPK;
  // XCD-local replica: consecutive blocks round-robin across 8 XCDs -> pick matching copy
  const unsigned short* khc = kh + (size_t)(i & 7) * KVSZ;
  const unsigned short* vhc = vh + (size_t)(i & 7) * KVSZ;

  __shared__ int   sidx[4][TOPK];      // per-wave private copies -> no __syncthreads
  __shared__ float sp[4][2][TOPK];

  sidx[w][l]      = (l < n)      ? irow[l]      : 0;
  sidx[w][l + 64] = (l + 64 < n) ? irow[l + 64] : 0;

  const int h0 = 2 * w, h1 = h0 + 1;
  const int g = l >> 3, gl = l & 7;
  const float* qrow = q + (size_t)i * (NH * 64);
  __half2 qa2[4], qb2[4];
  {
    float4 a0 = *(const float4*)&qrow[h0 * 64 + gl * 8];
    float4 a1 = *(const float4*)&qrow[h0 * 64 + gl * 8 + 4];
    float4 b0 = *(const float4*)&qrow[h1 * 64 + gl * 8];
    float4 b1 = *(const float4*)&qrow[h1 * 64 + gl * 8 + 4];
    qa2[0] = __floats2half2_rn(a0.x * 0.125f, a0.y * 0.125f);
    qa2[1] = __floats2half2_rn(a0.z * 0.125f, a0.w * 0.125f);
    qa2[2] = __floats2half2_rn(a1.x * 0.125f, a1.y * 0.125f);
    qa2[3] = __floats2half2_rn(a1.z * 0.125f, a1.w * 0.125f);
    qb2[0] = __floats2half2_rn(b0.x * 0.125f, b0.y * 0.125f);
    qb2[1] = __floats2half2_rn(b0.z * 0.125f, b0.w * 0.125f);
    qb2[2] = __floats2half2_rn(b1.x * 0.125f, b1.y * 0.125f);
    qb2[3] = __floats2half2_rn(b1.z * 0.125f, b1.w * 0.125f);
  }
  asm volatile("" ::: "memory");

#pragma unroll 4
  for (int pass = 0; pass < TOPK / 8; ++pass){
    const int j = pass * 8 + g;
    const size_t base = (size_t)sidx[w][j] * (NH * 64);
    uint4 u0 = *(const uint4*)(khc + base + h0 * 64 + gl * 8);
    uint4 u1 = *(const uint4*)(khc + base + h1 * 64 + gl * 8);
    __half2 acc0 = __floats2half2_rn(0.f, 0.f);
    __half2 acc1 = __floats2half2_rn(0.f, 0.f);
    acc0 = __hfma2(as_half2(u0.x), qa2[0], acc0);
    acc0 = __hfma2(as_half2(u0.y), qa2[1], acc0);
    acc0 = __hfma2(as_half2(u0.z), qa2[2], acc0);
    acc0 = __hfma2(as_half2(u0.w), qa2[3], acc0);
    acc1 = __hfma2(as_half2(u1.x), qb2[0], acc1);
    acc1 = __hfma2(as_half2(u1.y), qb2[1], acc1);
    acc1 = __hfma2(as_half2(u1.z), qb2[2], acc1);
    acc1 = __hfma2(as_half2(u1.w), qb2[3], acc1);
    float d0 = __low2float(acc0) + __high2float(acc0);
    float d1 = __low2float(acc1) + __high2float(acc1);
#pragma unroll
    for (int o = 1; o < 8; o <<= 1){ d0 += __shfl_xor(d0, o); d1 += __shfl_xor(d1, o); }
    if (gl == 0){ sp[w][0][j] = d0; sp[w][1][j] = d1; }
  }
  asm volatile("" ::: "memory");

  const bool v0 = (l < n), v1 = (l + 64 < n);
  {
    float s0 = v0 ? sp[w][0][l] : -1e30f, s1 = v1 ? sp[w][0][l + 64] : -1e30f;
    float m = wave_max(fmaxf(s0, s1));
    float e0 = v0 ? __expf(s0 - m) : 0.f;
    float e1 = v1 ? __expf(s1 - m) : 0.f;
    float inv = 1.f / wave_sum(e0 + e1);
    sp[w][0][l] = e0 * inv;
    sp[w][0][l + 64] = e1 * inv;
  }
  {
    float s0 = v0 ? sp[w][1][l] : -1e30f, s1 = v1 ? sp[w][1][l + 64] : -1e30f;
    float m = wave_max(fmaxf(s0, s1));
    float e0 = v0 ? __expf(s0 - m) : 0.f;
    float e1 = v1 ? __expf(s1 - m) : 0.f;
    float inv = 1.f / wave_sum(e0 + e1);
    sp[w][1][l] = e0 * inv;
    sp[w][1][l + 64] = e1 * inv;
  }
  asm volatile("" ::: "memory");

  const int kq = l >> 4;               // 0..3 key slot
  const int hp = (l >> 3) & 1;         // head parity within wave
  const int d8 = (l & 7) * 8;          // 8 dims per lane
  float o8[8] = {0,0,0,0,0,0,0,0};
#pragma unroll 4
  for (int pass = 0; pass < TOPK / 4; ++pass){
    const int j = pass * 4 + kq;
    const size_t base = (size_t)sidx[w][j] * (NH * 64);
    uint4 uv = *(const uint4*)(vhc + base + (h0 + hp) * 64 + d8);
    float p = sp[w][hp][j];
    __half2 va = as_half2(uv.x), vb = as_half2(uv.y), vc = as_half2(uv.z), vd = as_half2(uv.w);
    o8[0] = fmaf(p, __low2float(va),  o8[0]);
    o8[1] = fmaf(p, __high2float(va), o8[1]);
    o8[2] = fmaf(p, __low2float(vb),  o8[2]);
    o8[3] = fmaf(p, __high2float(vb), o8[3]);
    o8[4] = fmaf(p, __low2float(vc),  o8[4]);
    o8[5] = fmaf(p, __high2float(vc), o8[5]);
    o8[6] = fmaf(p, __low2float(vd),  o8[6]);
    o8[7] = fmaf(p, __high2float(vd), o8[7]);
  }
#pragma unroll
  for (int e = 0; e < 8; ++e){
    o8[e] += __shfl_xor(o8[e], 16);
    o8[e] += __shfl_xor(o8[e], 32);
  }
  if (l < 16){
    float* dst = &out[(size_t)i * (NH * 64) + (h0 + hp) * 64 + d8];
    *(float4*)dst       = make_float4(o8[0], o8[1], o8[2], o8[3]);
    *(float4*)(dst + 4) = make_float4(o8[4], o8[5], o8[6], o8[7]);
  }
}

extern "C" void kernel_launch(void* const* d_in, const int* in_sizes, int n_in,
                              void* d_out, int out_size, void* d_ws, size_t ws_size,
                              hipStream_t stream){
  const float* x   = (const float*)d_in[0];
  const float* qin = (const float*)d_in[1];
  const float* q   = (const float*)d_in[2];
  const float* k   = (const float*)d_in[3];
  const float* v   = (const float*)d_in[4];
  const float* wq  = (const float*)d_in[5];
  const float* wk  = (const float*)d_in[6];
  const float* lng = (const float*)d_in[7];
  const float* lnb = (const float*)d_in[8];
  const float* ww  = (const float*)d_in[9];
  float* out = (float*)d_out;

  float* ws = (float*)d_ws;
  // Dedicated regions (offsets in floats); total ~82 MB << ws (~268 MB)
  float* part = ws;                          // KP*2048*80 = 1,310,720
  float* wgt  = ws + 1310720;                // 32,768
  float* qi   = ws + 1343488;                // 2 partials: 4,194,304
  float* sc   = ws + 5537792;                // 4,194,304
  int*   idx  = (int*)(ws + 9732096);        // 262,144
  int*   cnt  = (int*)(ws + 9994240);        // 2,048
  unsigned short* kh  = (unsigned short*)(ws + 9996288);   // 8 replicas x 1,048,576 ush = 4,194,304 fl
  unsigned short* vh  = (unsigned short*)(ws + 14190592);  // 8 replicas x 1,048,576 ush
  unsigned short* kih = (unsigned short*)(ws + 18384896);  // 131,072 ush each below
  unsigned short* kim = (unsigned short*)(ws + 18450432);
  unsigned short* kil = (unsigned short*)(ws + 18515968);
  unsigned short* qeh = (unsigned short*)(ws + 18581504);
  unsigned short* qem = (unsigned short*)(ws + 18647040);
  unsigned short* qel = (unsigned short*)(ws + 18712576);
  unsigned short* Ah  = (unsigned short*)(ws + 18778112);  // 1,048,576 ush each (S*QIN)
  unsigned short* Al  = (unsigned short*)(ws + 19302400);
  unsigned short* Bh  = (unsigned short*)(ws + 19826688);  // 524,288 ush each (1024*QIN)
  unsigned short* Bl  = (unsigned short*)(ws + 20088832);

  hipLaunchKernelGGL(k_f1,     dim3(3840),   dim3(256), 0, stream,
                     x, wk, ww, part, qin, Ah, Al, k, kh, v, vh, wq, Bh, Bl);
  hipLaunchKernelGGL(k_f2,     dim3(1536),   dim3(256), 0, stream,
                     part, lng, lnb, kih, kim, kil, wgt, Ah, Al, Bh, Bl, qi);
  hipLaunchKernelGGL(k_f3,     dim3(512),    dim3(256), 0, stream,
                     qi, wgt, qeh, qem, qel);
  hipLaunchKernelGGL(k_scores, dim3(32, 32), dim3(256), 0, stream,
                     qeh, qem, qel, kih, kim, kil, sc);
  hipLaunchKernelGGL(k_topk,   dim3(2048),   dim3(256), 0, stream, sc, idx, cnt);
  hipLaunchKernelGGL(k_attn,   dim3(2048),   dim3(256), 0, stream, q, kh, vh, idx, cnt, out);
}

// Round 15
// 119.228 us; speedup vs baseline: 1.0002x; 1.0002x over previous
//
#include <hip/hip_runtime.h>
#include <hip/hip_bf16.h>
#include <hip/hip_fp16.h>
#include <math.h>

#define S 2048
#define DM 1024
#define QIN 512
#define HI 16
#define DI 64
#define NH 8
#define TOPK 128
#define LN_EPS 1e-5f
#define KP 8            // k_part split-K factor
#define KVSZ (S * NH * 64)   // elements per K/V replica (1,048,576)

typedef float f32x4 __attribute__((ext_vector_type(4)));
typedef short s16x8 __attribute__((ext_vector_type(8)));

__device__ __forceinline__ float wave_sum(float v){
#pragma unroll
  for (int o = 32; o; o >>= 1) v += __shfl_xor(v, o);
  return v;
}
__device__ __forceinline__ float wave_max(float v){
#pragma unroll
  for (int o = 32; o; o >>= 1) v = fmaxf(v, __shfl_xor(v, o));
  return v;
}
__device__ __forceinline__ unsigned short f2bf(float x){
  unsigned u = __float_as_uint(x);
  unsigned r = u + 0x7FFFu + ((u >> 16) & 1u);   // RN-even
  return (unsigned short)(r >> 16);
}
__device__ __forceinline__ float bf2f(unsigned short s){
  return __uint_as_float(((unsigned)s) << 16);
}
__device__ __forceinline__ unsigned short f2h(float x){
  return __half_as_ushort(__float2half_rn(x));
}
union UH2 { unsigned int u; __half2 h; };
__device__ __forceinline__ __half2 as_half2(unsigned int u){ UH2 x; x.u = u; return x.h; }

// 3-term (2-split): (ah+al)(bh+bl) dropping al*bl  [r4-r8 proven for qi]
#define MFMA3(ACC, AH, AL, BH, BL) \
  ACC = __builtin_amdgcn_mfma_f32_16x16x32_bf16(AH, BH, ACC, 0, 0, 0); \
  ACC = __builtin_amdgcn_mfma_f32_16x16x32_bf16(AH, BL, ACC, 0, 0, 0); \
  ACC = __builtin_amdgcn_mfma_f32_16x16x32_bf16(AL, BH, ACC, 0, 0, 0);

// 6-term (3-split): rel err ~2^-26, f32-class  [r11/r13 proven for scores]
#define MFMA6(ACC, AH, AM, AL, BH, BM, BL) \
  ACC = __builtin_amdgcn_mfma_f32_16x16x32_bf16(AH, BH, ACC, 0, 0, 0); \
  ACC = __builtin_amdgcn_mfma_f32_16x16x32_bf16(AH, BM, ACC, 0, 0, 0); \
  ACC = __builtin_amdgcn_mfma_f32_16x16x32_bf16(AM, BH, ACC, 0, 0, 0); \
  ACC = __builtin_amdgcn_mfma_f32_16x16x32_bf16(AH, BL, ACC, 0, 0, 0); \
  ACC = __builtin_amdgcn_mfma_f32_16x16x32_bf16(AL, BH, ACC, 0, 0, 0); \
  ACC = __builtin_amdgcn_mfma_f32_16x16x32_bf16(AM, BM, ACC, 0, 0, 0);

// ======== F1: fused [part-f32 (256) | prep-convert (3072, K/V -> 8 XCD replicas) | wq-trsplit (512)] ========
__global__ __launch_bounds__(256) void k_f1(const float* __restrict__ x,
                                            const float* __restrict__ wk,
                                            const float* __restrict__ ww,
                                            float* __restrict__ part,
                                            const float* __restrict__ qin,
                                            unsigned short* __restrict__ Ah,
                                            unsigned short* __restrict__ Al,
                                            const float* __restrict__ k,
                                            unsigned short* __restrict__ kh,
                                            const float* __restrict__ v,
                                            unsigned short* __restrict__ vh,
                                            const float* __restrict__ wq,
                                            unsigned short* __restrict__ Bh,
                                            unsigned short* __restrict__ Bl){
  __shared__ float As[32][68];
  __shared__ float Bs[32][84];
  const int bid = blockIdx.x;
  const int t = threadIdx.x;

  if (bid < 256){
    // ---- part: split-K f32 GEMM x(2048x1024) @ [wk|ww](1024x80)  [exact] ----
    const int kp = bid & 7;
    const int bm = bid >> 3;
    const int m0 = bm * 64;
    const int tm = (t & 15) * 4;
    const int tn = (t >> 4) * 5;
    float acc[4][5];
#pragma unroll
    for (int i = 0; i < 4; i++)
#pragma unroll
      for (int j = 0; j < 5; j++) acc[i][j] = 0.f;

    for (int kb = 0; kb < (DM / KP) / 32; ++kb){
      const int k0 = kp * (DM / KP) + kb * 32;
#pragma unroll
      for (int i = 0; i < 2; i++){
        int u = t + i * 256;
        int m = u >> 3, c4 = u & 7;
        float4 a = *(const float4*)&x[(size_t)(m0 + m) * DM + k0 + c4 * 4];
        As[c4*4+0][m] = a.x; As[c4*4+1][m] = a.y; As[c4*4+2][m] = a.z; As[c4*4+3][m] = a.w;
      }
#pragma unroll
      for (int i = 0; i < 10; i++){
        int u = t + i * 256;
        int kk = u / 80, nn = u % 80;
        float val = (nn < 64) ? wk[(size_t)(k0 + kk) * 64 + nn]
                              : ww[(size_t)(k0 + kk) * 16 + (nn - 64)];
        Bs[kk][nn] = val;
      }
      __syncthreads();
#pragma unroll
      for (int kk = 0; kk < 32; ++kk){
        float4 a = *(const float4*)&As[kk][tm];
        float av[4] = {a.x, a.y, a.z, a.w};
        float bb[5];
#pragma unroll
        for (int j = 0; j < 5; j++) bb[j] = Bs[kk][tn + j];
#pragma unroll
        for (int i = 0; i < 4; i++)
#pragma unroll
          for (int j = 0; j < 5; j++) acc[i][j] = fmaf(av[i], bb[j], acc[i][j]);
      }
      __syncthreads();
    }
    float* dst = part + (size_t)kp * S * 80;
#pragma unroll
    for (int i = 0; i < 4; i++)
#pragma unroll
      for (int j = 0; j < 5; j++)
        dst[(size_t)(m0 + tm + i) * 80 + tn + j] = acc[i][j];
    return;
  }

  if (bid < 256 + 3072){
    // ---- prep-convert: 2-split bf16(q_input); f16(K), f16(V) written to 8 XCD replicas ----
    const int SEG0 = S * QIN / 4;      // 262144
    const int SEG1 = KVSZ / 4;         // 262144
    int id = (bid - 256) * 256 + t;
    if (id < SEG0){
      float4 f = ((const float4*)qin)[id];
      ushort4 h, lo;
      h.x = f2bf(f.x); lo.x = f2bf(f.x - bf2f(h.x));
      h.y = f2bf(f.y); lo.y = f2bf(f.y - bf2f(h.y));
      h.z = f2bf(f.z); lo.z = f2bf(f.z - bf2f(h.z));
      h.w = f2bf(f.w); lo.w = f2bf(f.w - bf2f(h.w));
      ((ushort4*)Ah)[id] = h;
      ((ushort4*)Al)[id] = lo;
    } else if (id < SEG0 + SEG1){
      int j = id - SEG0;
      float4 f = ((const float4*)k)[j];
      ushort4 o;
      o.x = f2h(f.x); o.y = f2h(f.y); o.z = f2h(f.z); o.w = f2h(f.w);
#pragma unroll
      for (int c = 0; c < 8; ++c)
        ((ushort4*)(kh + (size_t)c * KVSZ))[j] = o;
    } else {
      int j = id - SEG0 - SEG1;
      float4 f = ((const float4*)v)[j];
      ushort4 o;
      o.x = f2h(f.x); o.y = f2h(f.y); o.z = f2h(f.z); o.w = f2h(f.w);
#pragma unroll
      for (int c = 0; c < 8; ++c)
        ((ushort4*)(vh + (size_t)c * KVSZ))[j] = o;
    }
    return;
  }

  // ---- wq (512x1024) -> transposed 2-split bf16 [n][k] ----
  {
    unsigned short (*lh)[33] = (unsigned short(*)[33])&As[0][0];
    unsigned short (*ll)[33] = (unsigned short(*)[33])&Bs[0][0];
    const int b2 = bid - 3328;          // 0..511
    const int k0 = (b2 & 15) * 32;
    const int n0 = (b2 >> 4) * 32;
    const int c = t & 31, r8 = t >> 5;
#pragma unroll
    for (int i = 0; i < 4; ++i){
      int kk = r8 + i * 8;
      float wv = wq[(size_t)(k0 + kk) * 1024 + n0 + c];
      unsigned short h = f2bf(wv);
      lh[c][kk] = h;
      ll[c][kk] = f2bf(wv - bf2f(h));
    }
    __syncthreads();
    const int kk = t & 31, nl = t >> 5;
#pragma unroll
    for (int i = 0; i < 4; ++i){
      int nn = nl + i * 8;
      Bh[(size_t)(n0 + nn) * QIN + k0 + kk] = lh[nn][kk];
      Bl[(size_t)(n0 + nn) * QIN + k0 + kk] = ll[nn][kk];
    }
  }
}

// ======== F2: fused [lnw -> ki-3split + wgt (512 blocks) | qi 3-term split-K=2 (1024 blocks)] ========
__global__ __launch_bounds__(256) void k_f2(const float* __restrict__ part,
                                            const float* __restrict__ g,
                                            const float* __restrict__ b,
                                            unsigned short* __restrict__ kih,
                                            unsigned short* __restrict__ kim,
                                            unsigned short* __restrict__ kil,
                                            float* __restrict__ wgt,
                                            const unsigned short* __restrict__ Ah,
                                            const unsigned short* __restrict__ Al,
                                            const unsigned short* __restrict__ Bh,
                                            const unsigned short* __restrict__ Bl,
                                            float* __restrict__ qi){
  const int bid = blockIdx.x;
  if (bid < 512){
    // ---- lnw: reduce KP partials, LayerNorm -> ki 3-split; wgt from cols 64..79 (exact f32) ----
    const int s = bid * 4 + (threadIdx.x >> 6);
    const int l = threadIdx.x & 63;
    float kv = 0.f;
#pragma unroll
    for (int p = 0; p < KP; p++) kv += part[(size_t)p * S * 80 + (size_t)s * 80 + l];
    float wv = 0.f;
    if (l < 16){
#pragma unroll
      for (int p = 0; p < KP; p++) wv += part[(size_t)p * S * 80 + (size_t)s * 80 + 64 + l];
    }
    float mu = wave_sum(kv) * (1.f / 64.f);
    float d  = kv - mu;
    float var = wave_sum(d * d) * (1.f / 64.f);
    float o = d * (1.f / sqrtf(var + LN_EPS)) * g[l] + b[l];
    unsigned short h = f2bf(o);
    float r1 = o - bf2f(h);
    unsigned short m = f2bf(r1);
    kih[(size_t)s * 64 + l] = h;
    kim[(size_t)s * 64 + l] = m;
    kil[(size_t)s * 64 + l] = f2bf(r1 - bf2f(m));
    if (l < 16) wgt[(size_t)s * 16 + l] = wv * 0.25f;   // HI^-0.5
    return;
  }
  // ---- qi = q_input @ w_q, 3-term MFMA, split-K=2 -> qi[kp] partials ----
  const int b2 = bid - 512;               // 0..1023
  const int kp = b2 & 1;
  const int bidx = b2 >> 1;               // 0..511
  const int bn = bidx & 15;
  const int bm = bidx >> 4;
  const int w = threadIdx.x >> 6, l = threadIdx.x & 63;
  const int r = l & 15, kg = l >> 4;
  const int m0 = bm * 64 + (w >> 1) * 32;
  const int n0 = bn * 64 + (w & 1) * 32;
  const int kbase = kp * 256;
  f32x4 acc00 = {0,0,0,0}, acc01 = {0,0,0,0}, acc10 = {0,0,0,0}, acc11 = {0,0,0,0};
  const size_t aoff = (size_t)(m0 + r) * QIN + kbase + kg * 8;
  const size_t boff = (size_t)(n0 + r) * QIN + kbase + kg * 8;
#pragma unroll 4
  for (int k0 = 0; k0 < 256; k0 += 32){
    s16x8 ah0 = *(const s16x8*)(Ah + aoff + k0);
    s16x8 ah1 = *(const s16x8*)(Ah + aoff + 16 * QIN + k0);
    s16x8 al0 = *(const s16x8*)(Al + aoff + k0);
    s16x8 al1 = *(const s16x8*)(Al + aoff + 16 * QIN + k0);
    s16x8 bh0 = *(const s16x8*)(Bh + boff + k0);
    s16x8 bh1 = *(const s16x8*)(Bh + boff + 16 * QIN + k0);
    s16x8 bl0 = *(const s16x8*)(Bl + boff + k0);
    s16x8 bl1 = *(const s16x8*)(Bl + boff + 16 * QIN + k0);
    MFMA3(acc00, ah0, al0, bh0, bl0)
    MFMA3(acc01, ah0, al0, bh1, bl1)
    MFMA3(acc10, ah1, al1, bh0, bl0)
    MFMA3(acc11, ah1, al1, bh1, bl1)
  }
  float* qip = qi + (size_t)kp * S * 1024;
#pragma unroll
  for (int j = 0; j < 4; ++j){
    qip[(size_t)(m0 +  0 + kg * 4 + j) * 1024 + n0 +  0 + r] = acc00[j];
    qip[(size_t)(m0 +  0 + kg * 4 + j) * 1024 + n0 + 16 + r] = acc01[j];
    qip[(size_t)(m0 + 16 + kg * 4 + j) * 1024 + n0 +  0 + r] = acc10[j];
    qip[(size_t)(m0 + 16 + kg * 4 + j) * 1024 + n0 + 16 + r] = acc11[j];
  }
}

// ======== F3: qeff (512 blocks) — sum qi partials, weighted head-sum, emit qe 3-split ========
__global__ __launch_bounds__(256) void k_f3(const float* __restrict__ qi,
                                            const float* __restrict__ wgt,
                                            unsigned short* __restrict__ qeh,
                                            unsigned short* __restrict__ qem,
                                            unsigned short* __restrict__ qel){
  const int id = blockIdx.x * 256 + threadIdx.x;  // S*64
  const int s = id >> 6, d = id & 63;
  const float* qiA = qi;
  const float* qiB = qi + (size_t)S * 1024;
  float acc = 0.f;
#pragma unroll
  for (int h = 0; h < 16; h++){
    float qv = qiA[(size_t)s * 1024 + h * 64 + d] + qiB[(size_t)s * 1024 + h * 64 + d];
    acc = fmaf(wgt[(size_t)s * 16 + h], qv, acc);
  }
  acc *= 0.125f;   // DI^-0.5
  unsigned short hh = f2bf(acc);
  float r1 = acc - bf2f(hh);
  unsigned short mm = f2bf(r1);
  qeh[(size_t)s * 64 + d] = hh;
  qem[(size_t)s * 64 + d] = mm;
  qel[(size_t)s * 64 + d] = f2bf(r1 - bf2f(mm));
}

// ---------------- kernel 5: scores = q_eff @ ki^T via 6-term 3-split MFMA (triangular) ----------------
__global__ __launch_bounds__(256) void k_scores(const unsigned short* __restrict__ qeh,
                                                const unsigned short* __restrict__ qem,
                                                const unsigned short* __restrict__ qel,
                                                const unsigned short* __restrict__ kih,
                                                const unsigned short* __restrict__ kim,
                                                const unsigned short* __restrict__ kil,
                                                float* __restrict__ sc){
  const int bj = blockIdx.x, bi = blockIdx.y;
  if (bj > bi) return;
  const int w = threadIdx.x >> 6, l = threadIdx.x & 63;
  const int r = l & 15, kg = l >> 4;
  const int m0 = bi * 64 + (w >> 1) * 32;
  const int n0 = bj * 64 + (w & 1) * 32;
  f32x4 acc00 = {0,0,0,0}, acc01 = {0,0,0,0}, acc10 = {0,0,0,0}, acc11 = {0,0,0,0};
  const size_t aoff = (size_t)(m0 + r) * 64 + kg * 8;
  const size_t boff = (size_t)(n0 + r) * 64 + kg * 8;
#pragma unroll
  for (int k0 = 0; k0 < 64; k0 += 32){
    s16x8 ah0 = *(const s16x8*)(qeh + aoff + k0);
    s16x8 ah1 = *(const s16x8*)(qeh + aoff + 16 * 64 + k0);
    s16x8 am0 = *(const s16x8*)(qem + aoff + k0);
    s16x8 am1 = *(const s16x8*)(qem + aoff + 16 * 64 + k0);
    s16x8 al0 = *(const s16x8*)(qel + aoff + k0);
    s16x8 al1 = *(const s16x8*)(qel + aoff + 16 * 64 + k0);
    s16x8 bh0 = *(const s16x8*)(kih + boff + k0);
    s16x8 bh1 = *(const s16x8*)(kih + boff + 16 * 64 + k0);
    s16x8 bm0 = *(const s16x8*)(kim + boff + k0);
    s16x8 bm1 = *(const s16x8*)(kim + boff + 16 * 64 + k0);
    s16x8 bl0 = *(const s16x8*)(kil + boff + k0);
    s16x8 bl1 = *(const s16x8*)(kil + boff + 16 * 64 + k0);
    MFMA6(acc00, ah0, am0, al0, bh0, bm0, bl0)
    MFMA6(acc01, ah0, am0, al0, bh1, bm1, bl1)
    MFMA6(acc10, ah1, am1, al1, bh0, bm0, bl0)
    MFMA6(acc11, ah1, am1, al1, bh1, bm1, bl1)
  }
#pragma unroll
  for (int j = 0; j < 4; ++j){
    sc[(size_t)(m0 +  0 + kg * 4 + j) * S + n0 +  0 + r] = acc00[j];
    sc[(size_t)(m0 +  0 + kg * 4 + j) * S + n0 + 16 + r] = acc01[j];
    sc[(size_t)(m0 + 16 + kg * 4 + j) * S + n0 +  0 + r] = acc10[j];
    sc[(size_t)(m0 + 16 + kg * 4 + j) * S + n0 + 16 + r] = acc11[j];
  }
}

// ---------------- kernel 6: per-row causal top-128 — radix select with candidate compaction ----------------
__global__ __launch_bounds__(256) void k_topk(const float* __restrict__ sc,
                                              int* __restrict__ idx,
                                              int* __restrict__ cnt){
  const int i = blockIdx.x, t = threadIdx.x;
  const int w = t >> 6, l = t & 63;
  const int n = i + 1;           // valid causal candidates
  int* outr = idx + (size_t)i * TOPK;
  if (n <= TOPK){
    for (int m = t; m < n; m += 256) outr[m] = m;
    if (t == 0) cnt[i] = n;
    return;
  }
  __shared__ unsigned int keys[S];
  __shared__ int lA[S];
  __shared__ int lB[S];
  __shared__ int hist[256];
  __shared__ int wtot[4];
  __shared__ int s_b, s_above, s_out, s_m;
  hist[t] = 0;
  if (t == 0) s_out = 0;
  __syncthreads();
  for (int j = t; j < n; j += 256){
    unsigned int u = __float_as_uint(sc[(size_t)i * S + j]);
    unsigned int kk = (u & 0x80000000u) ? ~u : (u | 0x80000000u);   // order-preserving key
    keys[j] = kk;
    atomicAdd(&hist[kk >> 24], 1);    // top-byte histogram fused into load
  }
  __syncthreads();
  int rem = TOPK;
  {
    const int h = hist[t];
    int vsc = h;
#pragma unroll
    for (int off = 1; off < 64; off <<= 1){
      int u = __shfl_down(vsc, off);
      if (l + off < 64) vsc += u;
    }
    if (l == 0) wtot[w] = vsc;
    __syncthreads();
    int later = 0;
#pragma unroll
    for (int ww = 1; ww < 4; ++ww) if (ww > w) later += wtot[ww];
    const int excl = vsc + later - h;
    if (excl < rem && excl + h >= rem){ s_b = t; s_above = excl; }
    __syncthreads();
  }
  int b = s_b;
  rem -= s_above;
  if (t == 0) s_m = 0;
  __syncthreads();
  for (int j = t; j < n; j += 256){
    int by = keys[j] >> 24;
    if (by > b){ int p = atomicAdd(&s_out, 1); outr[p] = j; }
    else if (by == b){ int p = atomicAdd(&s_m, 1); lA[p] = j; }
  }
  __syncthreads();
  int m = s_m;
  int* Lsrc = lA; int* Ldst = lB;
  bool done = false;
  if (m == rem){
    int base = TOPK - rem;
    for (int u = t; u < m; u += 256) outr[base + u] = Lsrc[u];
    done = true;
  }
  for (int p = 2; p >= 0 && !done; --p){
    const int sh = p * 8;
    __syncthreads();
    hist[t] = 0;
    __syncthreads();
    for (int u = t; u < m; u += 256) atomicAdd(&hist[(keys[Lsrc[u]] >> sh) & 255], 1);
    __syncthreads();
    {
      const int h = hist[t];
      int vsc = h;
#pragma unroll
      for (int off = 1; off < 64; off <<= 1){
        int u = __shfl_down(vsc, off);
        if (l + off < 64) vsc += u;
      }
      if (l == 0) wtot[w] = vsc;
      __syncthreads();
      int later = 0;
#pragma unroll
      for (int ww = 1; ww < 4; ++ww) if (ww > w) later += wtot[ww];
      const int excl = vsc + later - h;
      if (excl < rem && excl + h >= rem){ s_b = t; s_above = excl; }
      __syncthreads();
    }
    b = s_b;
    rem -= s_above;
    if (t == 0) s_m = 0;
    __syncthreads();
    for (int u = t; u < m; u += 256){
      int j = Lsrc[u]; int by = (keys[j] >> sh) & 255;
      if (by > b){ int p2 = atomicAdd(&s_out, 1); outr[p2] = j; }
      else if (by == b){ int p2 = atomicAdd(&s_m, 1); Ldst[p2] = j; }
    }
    __syncthreads();
    m = s_m;
    { int* tmp = Lsrc; Lsrc = Ldst; Ldst = tmp; }
    if (m == rem){
      int base = TOPK - rem;
      for (int u = t; u < m; u += 256) outr[base + u] = Lsrc[u];
      done = true;
    }
  }
  if (!done && t == 0){
    int base = TOPK - rem;
    for (int a = 0; a < rem; ++a){
      int mn = 1 << 30, pos = -1;
      for (int u = 0; u < m; ++u){ int j = Lsrc[u]; if (j < mn){ mn = j; pos = u; } }
      outr[base + a] = mn; Lsrc[pos] = 1 << 30;
    }
  }
  if (t == 0) cnt[i] = TOPK;
}

// ---------------- kernel 7: gathered sparse attention — f16 K/V (XCD-local replica), barrier-free ----------------
__global__ __launch_bounds__(256) void k_attn(const float* __restrict__ q,
                                              const unsigned short* __restrict__ kh,
                                              const unsigned short* __restrict__ vh,
                                              const int* __restrict__ idx,
                                              const int* __restrict__ cnt,
                                              float* __restrict__ out){
  const int i = blockIdx.x;
  const int w = threadIdx.x >> 6, l = threadIdx.x & 63;
  const int n = cnt[i];
  const int* irow = idx + (size_t)i * TOPK;
  // XCD-local replica: consecutive blocks round-robin across 8 XCDs -> pick matching copy
  const unsigned short* khc = kh + (size_t)(i & 7) * KVSZ;
  const unsigned short* vhc = vh + (size_t)(i & 7) * KVSZ;

  __shared__ int   sidx[4][TOPK];      // per-wave private copies -> no __syncthreads
  __shared__ float sp[4][2][TOPK];

  sidx[w][l]      = (l < n)      ? irow[l]      : 0;
  sidx[w][l + 64] = (l + 64 < n) ? irow[l + 64] : 0;

  const int h0 = 2 * w, h1 = h0 + 1;
  const int g = l >> 3, gl = l & 7;
  const float* qrow = q + (size_t)i * (NH * 64);
  __half2 qa2[4], qb2[4];
  {
    float4 a0 = *(const float4*)&qrow[h0 * 64 + gl * 8];
    float4 a1 = *(const float4*)&qrow[h0 * 64 + gl * 8 + 4];
    float4 b0 = *(const float4*)&qrow[h1 * 64 + gl * 8];
    float4 b1 = *(const float4*)&qrow[h1 * 64 + gl * 8 + 4];
    qa2[0] = __floats2half2_rn(a0.x * 0.125f, a0.y * 0.125f);
    qa2[1] = __floats2half2_rn(a0.z * 0.125f, a0.w * 0.125f);
    qa2[2] = __floats2half2_rn(a1.x * 0.125f, a1.y * 0.125f);
    qa2[3] = __floats2half2_rn(a1.z * 0.125f, a1.w * 0.125f);
    qb2[0] = __floats2half2_rn(b0.x * 0.125f, b0.y * 0.125f);
    qb2[1] = __floats2half2_rn(b0.z * 0.125f, b0.w * 0.125f);
    qb2[2] = __floats2half2_rn(b1.x * 0.125f, b1.y * 0.125f);
    qb2[3] = __floats2half2_rn(b1.z * 0.125f, b1.w * 0.125f);
  }
  asm volatile("" ::: "memory");

#pragma unroll 4
  for (int pass = 0; pass < TOPK / 8; ++pass){
    const int j = pass * 8 + g;
    const size_t base = (size_t)sidx[w][j] * (NH * 64);
    uint4 u0 = *(const uint4*)(khc + base + h0 * 64 + gl * 8);
    uint4 u1 = *(const uint4*)(khc + base + h1 * 64 + gl * 8);
    __half2 acc0 = __floats2half2_rn(0.f, 0.f);
    __half2 acc1 = __floats2half2_rn(0.f, 0.f);
    acc0 = __hfma2(as_half2(u0.x), qa2[0], acc0);
    acc0 = __hfma2(as_half2(u0.y), qa2[1], acc0);
    acc0 = __hfma2(as_half2(u0.z), qa2[2], acc0);
    acc0 = __hfma2(as_half2(u0.w), qa2[3], acc0);
    acc1 = __hfma2(as_half2(u1.x), qb2[0], acc1);
    acc1 = __hfma2(as_half2(u1.y), qb2[1], acc1);
    acc1 = __hfma2(as_half2(u1.z), qb2[2], acc1);
    acc1 = __hfma2(as_half2(u1.w), qb2[3], acc1);
    float d0 = __low2float(acc0) + __high2float(acc0);
    float d1 = __low2float(acc1) + __high2float(acc1);
#pragma unroll
    for (int o = 1; o < 8; o <<= 1){ d0 += __shfl_xor(d0, o); d1 += __shfl_xor(d1, o); }
    if (gl == 0){ sp[w][0][j] = d0; sp[w][1][j] = d1; }
  }
  asm volatile("" ::: "memory");

  const bool v0 = (l < n), v1 = (l + 64 < n);
  {
    float s0 = v0 ? sp[w][0][l] : -1e30f, s1 = v1 ? sp[w][0][l + 64] : -1e30f;
    float m = wave_max(fmaxf(s0, s1));
    float e0 = v0 ? __expf(s0 - m) : 0.f;
    float e1 = v1 ? __expf(s1 - m) : 0.f;
    float inv = 1.f / wave_sum(e0 + e1);
    sp[w][0][l] = e0 * inv;
    sp[w][0][l + 64] = e1 * inv;
  }
  {
    float s0 = v0 ? sp[w][1][l] : -1e30f, s1 = v1 ? sp[w][1][l + 64] : -1e30f;
    float m = wave_max(fmaxf(s0, s1));
    float e0 = v0 ? __expf(s0 - m) : 0.f;
    float e1 = v1 ? __expf(s1 - m) : 0.f;
    float inv = 1.f / wave_sum(e0 + e1);
    sp[w][1][l] = e0 * inv;
    sp[w][1][l + 64] = e1 * inv;
  }
  asm volatile("" ::: "memory");

  const int kq = l >> 4;               // 0..3 key slot
  const int hp = (l >> 3) & 1;         // head parity within wave
  const int d8 = (l & 7) * 8;          // 8 dims per lane
  float o8[8] = {0,0,0,0,0,0,0,0};
#pragma unroll 4
  for (int pass = 0; pass < TOPK / 4; ++pass){
    const int j = pass * 4 + kq;
    const size_t base = (size_t)sidx[w][j] * (NH * 64);
    uint4 uv = *(const uint4*)(vhc + base + (h0 + hp) * 64 + d8);
    float p = sp[w][hp][j];
    __half2 va = as_half2(uv.x), vb = as_half2(uv.y), vc = as_half2(uv.z), vd = as_half2(uv.w);
    o8[0] = fmaf(p, __low2float(va),  o8[0]);
    o8[1] = fmaf(p, __high2float(va), o8[1]);
    o8[2] = fmaf(p, __low2float(vb),  o8[2]);
    o8[3] = fmaf(p, __high2float(vb), o8[3]);
    o8[4] = fmaf(p, __low2float(vc),  o8[4]);
    o8[5] = fmaf(p, __high2float(vc), o8[5]);
    o8[6] = fmaf(p, __low2float(vd),  o8[6]);
    o8[7] = fmaf(p, __high2float(vd), o8[7]);
  }
#pragma unroll
  for (int e = 0; e < 8; ++e){
    o8[e] += __shfl_xor(o8[e], 16);
    o8[e] += __shfl_xor(o8[e], 32);
  }
  if (l < 16){
    float* dst = &out[(size_t)i * (NH * 64) + (h0 + hp) * 64 + d8];
    *(float4*)dst       = make_float4(o8[0], o8[1], o8[2], o8[3]);
    *(float4*)(dst + 4) = make_float4(o8[4], o8[5], o8[6], o8[7]);
  }
}

extern "C" void kernel_launch(void* const* d_in, const int* in_sizes, int n_in,
                              void* d_out, int out_size, void* d_ws, size_t ws_size,
                              hipStream_t stream){
  const float* x   = (const float*)d_in[0];
  const float* qin = (const float*)d_in[1];
  const float* q   = (const float*)d_in[2];
  const float* k   = (const float*)d_in[3];
  const float* v   = (const float*)d_in[4];
  const float* wq  = (const float*)d_in[5];
  const float* wk  = (const float*)d_in[6];
  const float* lng = (const float*)d_in[7];
  const float* lnb = (const float*)d_in[8];
  const float* ww  = (const float*)d_in[9];
  float* out = (float*)d_out;

  float* ws = (float*)d_ws;
  // Dedicated regions (offsets in floats); total ~82 MB << ws (~268 MB)
  float* part = ws;                          // KP*2048*80 = 1,310,720
  float* wgt  = ws + 1310720;                // 32,768
  float* qi   = ws + 1343488;                // 2 partials: 4,194,304
  float* sc   = ws + 5537792;                // 4,194,304
  int*   idx  = (int*)(ws + 9732096);        // 262,144
  int*   cnt  = (int*)(ws + 9994240);        // 2,048
  unsigned short* kh  = (unsigned short*)(ws + 9996288);   // 8 replicas x 1,048,576 ush = 4,194,304 fl
  unsigned short* vh  = (unsigned short*)(ws + 14190592);  // 8 replicas x 1,048,576 ush
  unsigned short* kih = (unsigned short*)(ws + 18384896);  // 131,072 ush each below
  unsigned short* kim = (unsigned short*)(ws + 18450432);
  unsigned short* kil = (unsigned short*)(ws + 18515968);
  unsigned short* qeh = (unsigned short*)(ws + 18581504);
  unsigned short* qem = (unsigned short*)(ws + 18647040);
  unsigned short* qel = (unsigned short*)(ws + 18712576);
  unsigned short* Ah  = (unsigned short*)(ws + 18778112);  // 1,048,576 ush each (S*QIN)
  unsigned short* Al  = (unsigned short*)(ws + 19302400);
  unsigned short* Bh  = (unsigned short*)(ws + 19826688);  // 524,288 ush each (1024*QIN)
  unsigned short* Bl  = (unsigned short*)(ws + 20088832);

  hipLaunchKernelGGL(k_f1,     dim3(3840),   dim3(256), 0, stream,
                     x, wk, ww, part, qin, Ah, Al, k, kh, v, vh, wq, Bh, Bl);
  hipLaunchKernelGGL(k_f2,     dim3(1536),   dim3(256), 0, stream,
                     part, lng, lnb, kih, kim, kil, wgt, Ah, Al, Bh, Bl, qi);
  hipLaunchKernelGGL(k_f3,     dim3(512),    dim3(256), 0, stream,
                     qi, wgt, qeh, qem, qel);
  hipLaunchKernelGGL(k_scores, dim3(32, 32), dim3(256), 0, stream,
                     qeh, qem, qel, kih, kim, kil, sc);
  hipLaunchKernelGGL(k_topk,   dim3(2048),   dim3(256), 0, stream, sc, idx, cnt);
  hipLaunchKernelGGL(k_attn,   dim3(2048),   dim3(256), 0, stream, q, kh, vh, idx, cnt, out);
}

// Round 16
// 97.877 us; speedup vs baseline: 1.2184x; 1.2181x over previous
//
#include <hip/hip_runtime.h>
#include <hip/hip_bf16.h>
#include <hip/hip_fp16.h>
#include <math.h>

#define S 2048
#define DM 1024
#define QIN 512
#define HI 16
#define DI 64
#define NH 8
#define TOPK 128
#define LN_EPS 1e-5f
#define KP 8            // k_part split-K factor
#define KVSZ (S * NH * 64)

typedef float f32x4 __attribute__((ext_vector_type(4)));
typedef short s16x8 __attribute__((ext_vector_type(8)));

__device__ __forceinline__ float wave_sum(float v){
#pragma unroll
  for (int o = 32; o; o >>= 1) v += __shfl_xor(v, o);
  return v;
}
__device__ __forceinline__ float wave_max(float v){
#pragma unroll
  for (int o = 32; o; o >>= 1) v = fmaxf(v, __shfl_xor(v, o));
  return v;
}
__device__ __forceinline__ unsigned short f2bf(float x){
  unsigned u = __float_as_uint(x);
  unsigned r = u + 0x7FFFu + ((u >> 16) & 1u);   // RN-even
  return (unsigned short)(r >> 16);
}
__device__ __forceinline__ float bf2f(unsigned short s){
  return __uint_as_float(((unsigned)s) << 16);
}
__device__ __forceinline__ unsigned short f2h(float x){
  return __half_as_ushort(__float2half_rn(x));
}
union UH2 { unsigned int u; __half2 h; };
__device__ __forceinline__ __half2 as_half2(unsigned int u){ UH2 x; x.u = u; return x.h; }

// 3-term (2-split): (ah+al)(bh+bl) dropping al*bl  [r4-r8 proven for qi]
#define MFMA3(ACC, AH, AL, BH, BL) \
  ACC = __builtin_amdgcn_mfma_f32_16x16x32_bf16(AH, BH, ACC, 0, 0, 0); \
  ACC = __builtin_amdgcn_mfma_f32_16x16x32_bf16(AH, BL, ACC, 0, 0, 0); \
  ACC = __builtin_amdgcn_mfma_f32_16x16x32_bf16(AL, BH, ACC, 0, 0, 0);

// 6-term (3-split): rel err ~2^-26, f32-class  [r11/r13 proven for scores]
#define MFMA6(ACC, AH, AM, AL, BH, BM, BL) \
  ACC = __builtin_amdgcn_mfma_f32_16x16x32_bf16(AH, BH, ACC, 0, 0, 0); \
  ACC = __builtin_amdgcn_mfma_f32_16x16x32_bf16(AH, BM, ACC, 0, 0, 0); \
  ACC = __builtin_amdgcn_mfma_f32_16x16x32_bf16(AM, BH, ACC, 0, 0, 0); \
  ACC = __builtin_amdgcn_mfma_f32_16x16x32_bf16(AH, BL, ACC, 0, 0, 0); \
  ACC = __builtin_amdgcn_mfma_f32_16x16x32_bf16(AL, BH, ACC, 0, 0, 0); \
  ACC = __builtin_amdgcn_mfma_f32_16x16x32_bf16(AM, BM, ACC, 0, 0, 0);

// ======== F1: fused [part-f32 (256) | prep-convert (3072) | wq-trsplit (512)] ========
__global__ __launch_bounds__(256) void k_f1(const float* __restrict__ x,
                                            const float* __restrict__ wk,
                                            const float* __restrict__ ww,
                                            float* __restrict__ part,
                                            const float* __restrict__ qin,
                                            unsigned short* __restrict__ Ah,
                                            unsigned short* __restrict__ Al,
                                            const float* __restrict__ k,
                                            unsigned short* __restrict__ kh,
                                            const float* __restrict__ v,
                                            unsigned short* __restrict__ vh,
                                            const float* __restrict__ wq,
                                            unsigned short* __restrict__ Bh,
                                            unsigned short* __restrict__ Bl){
  __shared__ float As[32][68];
  __shared__ float Bs[32][84];
  const int bid = blockIdx.x;
  const int t = threadIdx.x;

  if (bid < 256){
    // ---- part: split-K f32 GEMM x(2048x1024) @ [wk|ww](1024x80)  [exact] ----
    const int kp = bid & 7;
    const int bm = bid >> 3;
    const int m0 = bm * 64;
    const int tm = (t & 15) * 4;
    const int tn = (t >> 4) * 5;
    float acc[4][5];
#pragma unroll
    for (int i = 0; i < 4; i++)
#pragma unroll
      for (int j = 0; j < 5; j++) acc[i][j] = 0.f;

    for (int kb = 0; kb < (DM / KP) / 32; ++kb){
      const int k0 = kp * (DM / KP) + kb * 32;
#pragma unroll
      for (int i = 0; i < 2; i++){
        int u = t + i * 256;
        int m = u >> 3, c4 = u & 7;
        float4 a = *(const float4*)&x[(size_t)(m0 + m) * DM + k0 + c4 * 4];
        As[c4*4+0][m] = a.x; As[c4*4+1][m] = a.y; As[c4*4+2][m] = a.z; As[c4*4+3][m] = a.w;
      }
#pragma unroll
      for (int i = 0; i < 10; i++){
        int u = t + i * 256;
        int kk = u / 80, nn = u % 80;
        float val = (nn < 64) ? wk[(size_t)(k0 + kk) * 64 + nn]
                              : ww[(size_t)(k0 + kk) * 16 + (nn - 64)];
        Bs[kk][nn] = val;
      }
      __syncthreads();
#pragma unroll
      for (int kk = 0; kk < 32; ++kk){
        float4 a = *(const float4*)&As[kk][tm];
        float av[4] = {a.x, a.y, a.z, a.w};
        float bb[5];
#pragma unroll
        for (int j = 0; j < 5; j++) bb[j] = Bs[kk][tn + j];
#pragma unroll
        for (int i = 0; i < 4; i++)
#pragma unroll
          for (int j = 0; j < 5; j++) acc[i][j] = fmaf(av[i], bb[j], acc[i][j]);
      }
      __syncthreads();
    }
    float* dst = part + (size_t)kp * S * 80;
#pragma unroll
    for (int i = 0; i < 4; i++)
#pragma unroll
      for (int j = 0; j < 5; j++)
        dst[(size_t)(m0 + tm + i) * 80 + tn + j] = acc[i][j];
    return;
  }

  if (bid < 256 + 3072){
    // ---- prep-convert: 2-split bf16(q_input); f16(K); f16(V) ----
    const int SEG0 = S * QIN / 4;      // 262144
    const int SEG1 = KVSZ / 4;         // 262144
    int id = (bid - 256) * 256 + t;
    if (id < SEG0){
      float4 f = ((const float4*)qin)[id];
      ushort4 h, lo;
      h.x = f2bf(f.x); lo.x = f2bf(f.x - bf2f(h.x));
      h.y = f2bf(f.y); lo.y = f2bf(f.y - bf2f(h.y));
      h.z = f2bf(f.z); lo.z = f2bf(f.z - bf2f(h.z));
      h.w = f2bf(f.w); lo.w = f2bf(f.w - bf2f(h.w));
      ((ushort4*)Ah)[id] = h;
      ((ushort4*)Al)[id] = lo;
    } else if (id < SEG0 + SEG1){
      int j = id - SEG0;
      float4 f = ((const float4*)k)[j];
      ushort4 o;
      o.x = f2h(f.x); o.y = f2h(f.y); o.z = f2h(f.z); o.w = f2h(f.w);
      ((ushort4*)kh)[j] = o;
    } else {
      int j = id - SEG0 - SEG1;
      float4 f = ((const float4*)v)[j];
      ushort4 o;
      o.x = f2h(f.x); o.y = f2h(f.y); o.z = f2h(f.z); o.w = f2h(f.w);
      ((ushort4*)vh)[j] = o;
    }
    return;
  }

  // ---- wq (512x1024) -> transposed 2-split bf16 [n][k] ----
  {
    unsigned short (*lh)[33] = (unsigned short(*)[33])&As[0][0];
    unsigned short (*ll)[33] = (unsigned short(*)[33])&Bs[0][0];
    const int b2 = bid - 3328;          // 0..511
    const int k0 = (b2 & 15) * 32;
    const int n0 = (b2 >> 4) * 32;
    const int c = t & 31, r8 = t >> 5;
#pragma unroll
    for (int i = 0; i < 4; ++i){
      int kk = r8 + i * 8;
      float wv = wq[(size_t)(k0 + kk) * 1024 + n0 + c];
      unsigned short h = f2bf(wv);
      lh[c][kk] = h;
      ll[c][kk] = f2bf(wv - bf2f(h));
    }
    __syncthreads();
    const int kk = t & 31, nl = t >> 5;
#pragma unroll
    for (int i = 0; i < 4; ++i){
      int nn = nl + i * 8;
      Bh[(size_t)(n0 + nn) * QIN + k0 + kk] = lh[nn][kk];
      Bl[(size_t)(n0 + nn) * QIN + k0 + kk] = ll[nn][kk];
    }
  }
}

// ======== F2: fused [lnw -> ki-3split + wgt (512 blocks) | qi LDS-staged 3-term MFMA (512 blocks)] ========
__global__ __launch_bounds__(256) void k_f2(const float* __restrict__ part,
                                            const float* __restrict__ g,
                                            const float* __restrict__ b,
                                            unsigned short* __restrict__ kih,
                                            unsigned short* __restrict__ kim,
                                            unsigned short* __restrict__ kil,
                                            float* __restrict__ wgt,
                                            const unsigned short* __restrict__ Ah,
                                            const unsigned short* __restrict__ Al,
                                            const unsigned short* __restrict__ Bh,
                                            const unsigned short* __restrict__ Bl,
                                            float* __restrict__ qi){
  __shared__ short Ash[64][72];
  __shared__ short Asl[64][72];
  __shared__ short Bsh[64][72];
  __shared__ short Bsl[64][72];
  const int bid = blockIdx.x;
  const int t = threadIdx.x;
  if (bid < 512){
    // ---- lnw: reduce KP partials, LayerNorm -> ki 3-split; wgt from cols 64..79 (exact f32) ----
    const int s = bid * 4 + (t >> 6);
    const int l = t & 63;
    float kv = 0.f;
#pragma unroll
    for (int p = 0; p < KP; p++) kv += part[(size_t)p * S * 80 + (size_t)s * 80 + l];
    float wv = 0.f;
    if (l < 16){
#pragma unroll
      for (int p = 0; p < KP; p++) wv += part[(size_t)p * S * 80 + (size_t)s * 80 + 64 + l];
    }
    float mu = wave_sum(kv) * (1.f / 64.f);
    float d  = kv - mu;
    float var = wave_sum(d * d) * (1.f / 64.f);
    float o = d * (1.f / sqrtf(var + LN_EPS)) * g[l] + b[l];
    unsigned short h = f2bf(o);
    float r1 = o - bf2f(h);
    unsigned short m = f2bf(r1);
    kih[(size_t)s * 64 + l] = h;
    kim[(size_t)s * 64 + l] = m;
    kil[(size_t)s * 64 + l] = f2bf(r1 - bf2f(m));
    if (l < 16) wgt[(size_t)s * 16 + l] = wv * 0.25f;   // HI^-0.5
    return;
  }
  // ---- qi = q_input @ w_q: LDS-staged 64x64 tile, 3-term MFMA ----
  const int b2 = bid - 512;               // 0..511
  const int bn = b2 & 15;                 // 1024/64
  const int bm = b2 >> 4;                 // 2048/64
  const int w = t >> 6, l = t & 63;
  const int r = l & 15, kg = l >> 4;
  const int m0 = bm * 64 + (w >> 1) * 32; // global row base for this wave's quadrant
  const int n0 = bn * 64 + (w & 1) * 32;
  const int mq = (w >> 1) * 32;           // LDS-local quadrant bases
  const int nq = (w & 1) * 32;
  const int srow = t >> 3;                // staging: thread -> (row, col8)
  const int scol = (t & 7) * 8;

  f32x4 acc00 = {0,0,0,0}, acc01 = {0,0,0,0}, acc10 = {0,0,0,0}, acc11 = {0,0,0,0};

  for (int kb = 0; kb < QIN / 64; ++kb){
    const int k0 = kb * 64;
    // stage 64x64 A(h,l) and B(h,l) tiles, coalesced (8 lanes cover one 128B row-segment)
#pragma unroll
    for (int i = 0; i < 2; ++i){
      int row = srow + i * 32;
      size_t ga = (size_t)(bm * 64 + row) * QIN + k0 + scol;
      size_t gb = (size_t)(bn * 64 + row) * QIN + k0 + scol;
      *(s16x8*)&Ash[row][scol] = *(const s16x8*)(Ah + ga);
      *(s16x8*)&Asl[row][scol] = *(const s16x8*)(Al + ga);
      *(s16x8*)&Bsh[row][scol] = *(const s16x8*)(Bh + gb);
      *(s16x8*)&Bsl[row][scol] = *(const s16x8*)(Bl + gb);
    }
    __syncthreads();
#pragma unroll
    for (int ks = 0; ks < 2; ++ks){
      const int ko = ks * 32 + kg * 8;
      s16x8 ah0 = *(const s16x8*)&Ash[mq + r][ko];
      s16x8 ah1 = *(const s16x8*)&Ash[mq + 16 + r][ko];
      s16x8 al0 = *(const s16x8*)&Asl[mq + r][ko];
      s16x8 al1 = *(const s16x8*)&Asl[mq + 16 + r][ko];
      s16x8 bh0 = *(const s16x8*)&Bsh[nq + r][ko];
      s16x8 bh1 = *(const s16x8*)&Bsh[nq + 16 + r][ko];
      s16x8 bl0 = *(const s16x8*)&Bsl[nq + r][ko];
      s16x8 bl1 = *(const s16x8*)&Bsl[nq + 16 + r][ko];
      MFMA3(acc00, ah0, al0, bh0, bl0)
      MFMA3(acc01, ah0, al0, bh1, bl1)
      MFMA3(acc10, ah1, al1, bh0, bl0)
      MFMA3(acc11, ah1, al1, bh1, bl1)
    }
    __syncthreads();
  }
#pragma unroll
  for (int j = 0; j < 4; ++j){
    qi[(size_t)(m0 +  0 + kg * 4 + j) * 1024 + n0 +  0 + r] = acc00[j];
    qi[(size_t)(m0 +  0 + kg * 4 + j) * 1024 + n0 + 16 + r] = acc01[j];
    qi[(size_t)(m0 + 16 + kg * 4 + j) * 1024 + n0 +  0 + r] = acc10[j];
    qi[(size_t)(m0 + 16 + kg * 4 + j) * 1024 + n0 + 16 + r] = acc11[j];
  }
}

// ======== F3: qeff (512 blocks) — weighted head-sum of qi, emit qe 3-split ========
__global__ __launch_bounds__(256) void k_f3(const float* __restrict__ qi,
                                            const float* __restrict__ wgt,
                                            unsigned short* __restrict__ qeh,
                                            unsigned short* __restrict__ qem,
                                            unsigned short* __restrict__ qel){
  const int id = blockIdx.x * 256 + threadIdx.x;  // S*64
  const int s = id >> 6, d = id & 63;
  float acc = 0.f;
#pragma unroll
  for (int h = 0; h < 16; h++)
    acc = fmaf(wgt[(size_t)s * 16 + h], qi[(size_t)s * 1024 + h * 64 + d], acc);
  acc *= 0.125f;   // DI^-0.5
  unsigned short hh = f2bf(acc);
  float r1 = acc - bf2f(hh);
  unsigned short mm = f2bf(r1);
  qeh[(size_t)s * 64 + d] = hh;
  qem[(size_t)s * 64 + d] = mm;
  qel[(size_t)s * 64 + d] = f2bf(r1 - bf2f(mm));
}

// ---------------- kernel 5: scores = q_eff @ ki^T via 6-term 3-split MFMA (triangular) ----------------
__global__ __launch_bounds__(256) void k_scores(const unsigned short* __restrict__ qeh,
                                                const unsigned short* __restrict__ qem,
                                                const unsigned short* __restrict__ qel,
                                                const unsigned short* __restrict__ kih,
                                                const unsigned short* __restrict__ kim,
                                                const unsigned short* __restrict__ kil,
                                                float* __restrict__ sc){
  const int bj = blockIdx.x, bi = blockIdx.y;
  if (bj > bi) return;
  const int w = threadIdx.x >> 6, l = threadIdx.x & 63;
  const int r = l & 15, kg = l >> 4;
  const int m0 = bi * 64 + (w >> 1) * 32;
  const int n0 = bj * 64 + (w & 1) * 32;
  f32x4 acc00 = {0,0,0,0}, acc01 = {0,0,0,0}, acc10 = {0,0,0,0}, acc11 = {0,0,0,0};
  const size_t aoff = (size_t)(m0 + r) * 64 + kg * 8;
  const size_t boff = (size_t)(n0 + r) * 64 + kg * 8;
#pragma unroll
  for (int k0 = 0; k0 < 64; k0 += 32){
    s16x8 ah0 = *(const s16x8*)(qeh + aoff + k0);
    s16x8 ah1 = *(const s16x8*)(qeh + aoff + 16 * 64 + k0);
    s16x8 am0 = *(const s16x8*)(qem + aoff + k0);
    s16x8 am1 = *(const s16x8*)(qem + aoff + 16 * 64 + k0);
    s16x8 al0 = *(const s16x8*)(qel + aoff + k0);
    s16x8 al1 = *(const s16x8*)(qel + aoff + 16 * 64 + k0);
    s16x8 bh0 = *(const s16x8*)(kih + boff + k0);
    s16x8 bh1 = *(const s16x8*)(kih + boff + 16 * 64 + k0);
    s16x8 bm0 = *(const s16x8*)(kim + boff + k0);
    s16x8 bm1 = *(const s16x8*)(kim + boff + 16 * 64 + k0);
    s16x8 bl0 = *(const s16x8*)(kil + boff + k0);
    s16x8 bl1 = *(const s16x8*)(kil + boff + 16 * 64 + k0);
    MFMA6(acc00, ah0, am0, al0, bh0, bm0, bl0)
    MFMA6(acc01, ah0, am0, al0, bh1, bm1, bl1)
    MFMA6(acc10, ah1, am1, al1, bh0, bm0, bl0)
    MFMA6(acc11, ah1, am1, al1, bh1, bm1, bl1)
  }
#pragma unroll
  for (int j = 0; j < 4; ++j){
    sc[(size_t)(m0 +  0 + kg * 4 + j) * S + n0 +  0 + r] = acc00[j];
    sc[(size_t)(m0 +  0 + kg * 4 + j) * S + n0 + 16 + r] = acc01[j];
    sc[(size_t)(m0 + 16 + kg * 4 + j) * S + n0 +  0 + r] = acc10[j];
    sc[(size_t)(m0 + 16 + kg * 4 + j) * S + n0 + 16 + r] = acc11[j];
  }
}

// ---------------- kernel 6: per-row causal top-128 — radix select with candidate compaction ----------------
__global__ __launch_bounds__(256) void k_topk(const float* __restrict__ sc,
                                              int* __restrict__ idx,
                                              int* __restrict__ cnt){
  const int i = blockIdx.x, t = threadIdx.x;
  const int w = t >> 6, l = t & 63;
  const int n = i + 1;           // valid causal candidates
  int* outr = idx + (size_t)i * TOPK;
  if (n <= TOPK){
    for (int m = t; m < n; m += 256) outr[m] = m;
    if (t == 0) cnt[i] = n;
    return;
  }
  __shared__ unsigned int keys[S];
  __shared__ int lA[S];
  __shared__ int lB[S];
  __shared__ int hist[256];
  __shared__ int wtot[4];
  __shared__ int s_b, s_above, s_out, s_m;
  hist[t] = 0;
  if (t == 0) s_out = 0;
  __syncthreads();
  for (int j = t; j < n; j += 256){
    unsigned int u = __float_as_uint(sc[(size_t)i * S + j]);
    unsigned int kk = (u & 0x80000000u) ? ~u : (u | 0x80000000u);   // order-preserving key
    keys[j] = kk;
    atomicAdd(&hist[kk >> 24], 1);    // top-byte histogram fused into load
  }
  __syncthreads();
  int rem = TOPK;
  {
    const int h = hist[t];
    int vsc = h;
#pragma unroll
    for (int off = 1; off < 64; off <<= 1){
      int u = __shfl_down(vsc, off);
      if (l + off < 64) vsc += u;
    }
    if (l == 0) wtot[w] = vsc;
    __syncthreads();
    int later = 0;
#pragma unroll
    for (int ww = 1; ww < 4; ++ww) if (ww > w) later += wtot[ww];
    const int excl = vsc + later - h;
    if (excl < rem && excl + h >= rem){ s_b = t; s_above = excl; }
    __syncthreads();
  }
  int b = s_b;
  rem -= s_above;
  if (t == 0) s_m = 0;
  __syncthreads();
  for (int j = t; j < n; j += 256){
    int by = keys[j] >> 24;
    if (by > b){ int p = atomicAdd(&s_out, 1); outr[p] = j; }
    else if (by == b){ int p = atomicAdd(&s_m, 1); lA[p] = j; }
  }
  __syncthreads();
  int m = s_m;
  int* Lsrc = lA; int* Ldst = lB;
  bool done = false;
  if (m == rem){
    int base = TOPK - rem;
    for (int u = t; u < m; u += 256) outr[base + u] = Lsrc[u];
    done = true;
  }
  for (int p = 2; p >= 0 && !done; --p){
    const int sh = p * 8;
    __syncthreads();
    hist[t] = 0;
    __syncthreads();
    for (int u = t; u < m; u += 256) atomicAdd(&hist[(keys[Lsrc[u]] >> sh) & 255], 1);
    __syncthreads();
    {
      const int h = hist[t];
      int vsc = h;
#pragma unroll
      for (int off = 1; off < 64; off <<= 1){
        int u = __shfl_down(vsc, off);
        if (l + off < 64) vsc += u;
      }
      if (l == 0) wtot[w] = vsc;
      __syncthreads();
      int later = 0;
#pragma unroll
      for (int ww = 1; ww < 4; ++ww) if (ww > w) later += wtot[ww];
      const int excl = vsc + later - h;
      if (excl < rem && excl + h >= rem){ s_b = t; s_above = excl; }
      __syncthreads();
    }
    b = s_b;
    rem -= s_above;
    if (t == 0) s_m = 0;
    __syncthreads();
    for (int u = t; u < m; u += 256){
      int j = Lsrc[u]; int by = (keys[j] >> sh) & 255;
      if (by > b){ int p2 = atomicAdd(&s_out, 1); outr[p2] = j; }
      else if (by == b){ int p2 = atomicAdd(&s_m, 1); Ldst[p2] = j; }
    }
    __syncthreads();
    m = s_m;
    { int* tmp = Lsrc; Lsrc = Ldst; Ldst = tmp; }
    if (m == rem){
      int base = TOPK - rem;
      for (int u = t; u < m; u += 256) outr[base + u] = Lsrc[u];
      done = true;
    }
  }
  if (!done && t == 0){
    int base = TOPK - rem;
    for (int a = 0; a < rem; ++a){
      int mn = 1 << 30, pos = -1;
      for (int u = 0; u < m; ++u){ int j = Lsrc[u]; if (j < mn){ mn = j; pos = u; } }
      outr[base + a] = mn; Lsrc[pos] = 1 << 30;
    }
  }
  if (t == 0) cnt[i] = TOPK;
}

// ---------------- kernel 7: gathered sparse attention — f16 K/V, 16B/lane PV, barrier-free ----------------
__global__ __launch_bounds__(256) void k_attn(const float* __restrict__ q,
                                              const unsigned short* __restrict__ kh,
                                              const unsigned short* __restrict__ vh,
                                              const int* __restrict__ idx,
                                              const int* __restrict__ cnt,
                                              float* __restrict__ out){
  const int i = blockIdx.x;
  const int w = threadIdx.x >> 6, l = threadIdx.x & 63;
  const int n = cnt[i];
  const int* irow = idx + (size_t)i * TOPK;

  __shared__ int   sidx[4][TOPK];      // per-wave private copies -> no __syncthreads
  __shared__ float sp[4][2][TOPK];

  sidx[w][l]      = (l < n)      ? irow[l]      : 0;
  sidx[w][l + 64] = (l + 64 < n) ? irow[l + 64] : 0;

  const int h0 = 2 * w, h1 = h0 + 1;
  const int g = l >> 3, gl = l & 7;
  const float* qrow = q + (size_t)i * (NH * 64);
  __half2 qa2[4], qb2[4];
  {
    float4 a0 = *(const float4*)&qrow[h0 * 64 + gl * 8];
    float4 a1 = *(const float4*)&qrow[h0 * 64 + gl * 8 + 4];
    float4 b0 = *(const float4*)&qrow[h1 * 64 + gl * 8];
    float4 b1 = *(const float4*)&qrow[h1 * 64 + gl * 8 + 4];
    qa2[0] = __floats2half2_rn(a0.x * 0.125f, a0.y * 0.125f);
    qa2[1] = __floats2half2_rn(a0.z * 0.125f, a0.w * 0.125f);
    qa2[2] = __floats2half2_rn(a1.x * 0.125f, a1.y * 0.125f);
    qa2[3] = __floats2half2_rn(a1.z * 0.125f, a1.w * 0.125f);
    qb2[0] = __floats2half2_rn(b0.x * 0.125f, b0.y * 0.125f);
    qb2[1] = __floats2half2_rn(b0.z * 0.125f, b0.w * 0.125f);
    qb2[2] = __floats2half2_rn(b1.x * 0.125f, b1.y * 0.125f);
    qb2[3] = __floats2half2_rn(b1.z * 0.125f, b1.w * 0.125f);
  }
  asm volatile("" ::: "memory");

#pragma unroll 4
  for (int pass = 0; pass < TOPK / 8; ++pass){
    const int j = pass * 8 + g;
    const size_t base = (size_t)sidx[w][j] * (NH * 64);
    uint4 u0 = *(const uint4*)(kh + base + h0 * 64 + gl * 8);
    uint4 u1 = *(const uint4*)(kh + base + h1 * 64 + gl * 8);
    __half2 acc0 = __floats2half2_rn(0.f, 0.f);
    __half2 acc1 = __floats2half2_rn(0.f, 0.f);
    acc0 = __hfma2(as_half2(u0.x), qa2[0], acc0);
    acc0 = __hfma2(as_half2(u0.y), qa2[1], acc0);
    acc0 = __hfma2(as_half2(u0.z), qa2[2], acc0);
    acc0 = __hfma2(as_half2(u0.w), qa2[3], acc0);
    acc1 = __hfma2(as_half2(u1.x), qb2[0], acc1);
    acc1 = __hfma2(as_half2(u1.y), qb2[1], acc1);
    acc1 = __hfma2(as_half2(u1.z), qb2[2], acc1);
    acc1 = __hfma2(as_half2(u1.w), qb2[3], acc1);
    float d0 = __low2float(acc0) + __high2float(acc0);
    float d1 = __low2float(acc1) + __high2float(acc1);
#pragma unroll
    for (int o = 1; o < 8; o <<= 1){ d0 += __shfl_xor(d0, o); d1 += __shfl_xor(d1, o); }
    if (gl == 0){ sp[w][0][j] = d0; sp[w][1][j] = d1; }
  }
  asm volatile("" ::: "memory");

  const bool v0 = (l < n), v1 = (l + 64 < n);
  {
    float s0 = v0 ? sp[w][0][l] : -1e30f, s1 = v1 ? sp[w][0][l + 64] : -1e30f;
    float m = wave_max(fmaxf(s0, s1));
    float e0 = v0 ? __expf(s0 - m) : 0.f;
    float e1 = v1 ? __expf(s1 - m) : 0.f;
    float inv = 1.f / wave_sum(e0 + e1);
    sp[w][0][l] = e0 * inv;
    sp[w][0][l + 64] = e1 * inv;
  }
  {
    float s0 = v0 ? sp[w][1][l] : -1e30f, s1 = v1 ? sp[w][1][l + 64] : -1e30f;
    float m = wave_max(fmaxf(s0, s1));
    float e0 = v0 ? __expf(s0 - m) : 0.f;
    float e1 = v1 ? __expf(s1 - m) : 0.f;
    float inv = 1.f / wave_sum(e0 + e1);
    sp[w][1][l] = e0 * inv;
    sp[w][1][l + 64] = e1 * inv;
  }
  asm volatile("" ::: "memory");

  const int kq = l >> 4;               // 0..3 key slot
  const int hp = (l >> 3) & 1;         // head parity within wave
  const int d8 = (l & 7) * 8;          // 8 dims per lane
  float o8[8] = {0,0,0,0,0,0,0,0};
#pragma unroll 4
  for (int pass = 0; pass < TOPK / 4; ++pass){
    const int j = pass * 4 + kq;
    const size_t base = (size_t)sidx[w][j] * (NH * 64);
    uint4 uv = *(const uint4*)(vh + base + (h0 + hp) * 64 + d8);
    float p = sp[w][hp][j];
    __half2 va = as_half2(uv.x), vb = as_half2(uv.y), vc = as_half2(uv.z), vd = as_half2(uv.w);
    o8[0] = fmaf(p, __low2float(va),  o8[0]);
    o8[1] = fmaf(p, __high2float(va), o8[1]);
    o8[2] = fmaf(p, __low2float(vb),  o8[2]);
    o8[3] = fmaf(p, __high2float(vb), o8[3]);
    o8[4] = fmaf(p, __low2float(vc),  o8[4]);
    o8[5] = fmaf(p, __high2float(vc), o8[5]);
    o8[6] = fmaf(p, __low2float(vd),  o8[6]);
    o8[7] = fmaf(p, __high2float(vd), o8[7]);
  }
#pragma unroll
  for (int e = 0; e < 8; ++e){
    o8[e] += __shfl_xor(o8[e], 16);
    o8[e] += __shfl_xor(o8[e], 32);
  }
  if (l < 16){
    float* dst = &out[(size_t)i * (NH * 64) + (h0 + hp) * 64 + d8];
    *(float4*)dst       = make_float4(o8[0], o8[1], o8[2], o8[3]);
    *(float4*)(dst + 4) = make_float4(o8[4], o8[5], o8[6], o8[7]);
  }
}

extern "C" void kernel_launch(void* const* d_in, const int* in_sizes, int n_in,
                              void* d_out, int out_size, void* d_ws, size_t ws_size,
                              hipStream_t stream){
  const float* x   = (const float*)d_in[0];
  const float* qin = (const float*)d_in[1];
  const float* q   = (const float*)d_in[2];
  const float* k   = (const float*)d_in[3];
  const float* v   = (const float*)d_in[4];
  const float* wq  = (const float*)d_in[5];
  const float* wk  = (const float*)d_in[6];
  const float* lng = (const float*)d_in[7];
  const float* lnb = (const float*)d_in[8];
  const float* ww  = (const float*)d_in[9];
  float* out = (float*)d_out;

  float* ws = (float*)d_ws;
  // Dedicated regions (offsets in floats); total ~44 MB << ws (~268 MB)
  float* part = ws;                          // KP*2048*80 = 1,310,720
  float* wgt  = ws + 1310720;                // 32,768
  float* qi   = ws + 1343488;                // 2,097,152
  float* sc   = ws + 3440640;                // 4,194,304
  int*   idx  = (int*)(ws + 7634944);        // 262,144
  int*   cnt  = (int*)(ws + 7897088);        // 2,048
  unsigned short* kh  = (unsigned short*)(ws + 7899136);   // 1,048,576 ush
  unsigned short* vh  = (unsigned short*)(ws + 8423424);   // 1,048,576 ush
  unsigned short* kih = (unsigned short*)(ws + 8947712);   // 131,072 ush each below
  unsigned short* kim = (unsigned short*)(ws + 9013248);
  unsigned short* kil = (unsigned short*)(ws + 9078784);
  unsigned short* qeh = (unsigned short*)(ws + 9144320);
  unsigned short* qem = (unsigned short*)(ws + 9209856);
  unsigned short* qel = (unsigned short*)(ws + 9275392);
  unsigned short* Ah  = (unsigned short*)(ws + 9340928);   // 1,048,576 ush each (S*QIN)
  unsigned short* Al  = (unsigned short*)(ws + 9865216);
  unsigned short* Bh  = (unsigned short*)(ws + 10389504);  // 524,288 ush each (1024*QIN)
  unsigned short* Bl  = (unsigned short*)(ws + 10651648);

  hipLaunchKernelGGL(k_f1,     dim3(3840),   dim3(256), 0, stream,
                     x, wk, ww, part, qin, Ah, Al, k, kh, v, vh, wq, Bh, Bl);
  hipLaunchKernelGGL(k_f2,     dim3(1024),   dim3(256), 0, stream,
                     part, lng, lnb, kih, kim, kil, wgt, Ah, Al, Bh, Bl, qi);
  hipLaunchKernelGGL(k_f3,     dim3(512),    dim3(256), 0, stream,
                     qi, wgt, qeh, qem, qel);
  hipLaunchKernelGGL(k_scores, dim3(32, 32), dim3(256), 0, stream,
                     qeh, qem, qel, kih, kim, kil, sc);
  hipLaunchKernelGGL(k_topk,   dim3(2048),   dim3(256), 0, stream, sc, idx, cnt);
  hipLaunchKernelGGL(k_attn,   dim3(2048),   dim3(256), 0, stream, q, kh, vh, idx, cnt, out);
}